// Round 5
// baseline (254.601 us; speedup 1.0000x reference)
//
#include <hip/hip_runtime.h>
#include <math.h>

#define B_ 16
#define SEQ_ 8192
#define C_ 192
#define H_ 16
#define OV_ 4
#define G_ 6
#define K_ 1024
#define D_ 8
#define DG_ 2048
#define W_ 512
#define T_ 128
#define TT 4
#define OUT_ELEMS (B_ * SEQ_ * C_)   // 25165824

// workspace layout:
//   pd_perm : float [G*DG*D]  = 98304 floats   @ byte 0
//   pu_perm : float [G*D*DG]  = 98304 floats   @ byte 393216
//   cbn_d   : double[G*K*D]   = 49152 doubles  @ byte 786432
// total = 1179648 bytes

// d' = h*128 + ul  <->  group-local d = ul*16 + h,  u = g*128 + ul = o*192 + c
// o*192 + c == u, so z addresses are LINEAR in u:
//   z[t][dp] = zb[(h*512 + (tc*4+t)*4)*192 + g*128 + ul]
//
// Register budget notes (the whole game is VGPR <= 64 quantum):
//  - phase 1: acc[4][4] fp64 (32) + zv (8) + pa/pb (8) + addr ~ 58  <- peak
//  - phase 2: wave-per-frame, ONE cbn row in flight (unroll 1):
//      zr[8] (16) + row (16) + best/key + addr ~ 45   (was 64+: hoisted
//      ze 32 + cd2 32 in round 3 -> 68-reg alloc -> occupancy halved)
//  - plain __launch_bounds__(256): min-waves clamps force scratch spills
//    (rounds 1-2: +190 MB HBM fetch AND write).

__global__ __launch_bounds__(256) void vq_prep(
    const float* __restrict__ pd, const float* __restrict__ pu,
    const float* __restrict__ cb,
    float* __restrict__ pd_p, float* __restrict__ pu_p,
    double* __restrict__ cbn, float* __restrict__ loss_slots)
{
  int i = blockIdx.x * 256 + threadIdx.x;
  if (i < 98304) {                       // pd_perm[g][d'][e]
    int e = i & 7, dp = (i >> 3) & 2047, g = i >> 14;
    int h = dp >> 7, ul = dp & 127, d = (ul << 4) + h;
    pd_p[i] = pd[(g << 14) + (d << 3) + e];
  } else if (i < 196608) {               // pu_perm[g][e][d']
    int i2 = i - 98304;
    int dp = i2 & 2047, e = (i2 >> 11) & 7, g = i2 >> 14;
    int h = dp >> 7, ul = dp & 127, d = (ul << 4) + h;
    pu_p[i2] = pu[(g << 14) + (e << 11) + d];
  } else if (i < 202752) {               // normalized codebooks, fp64
    int j = i - 196608;                  // j = g*1024 + k
    const float* row = cb + (j << 3);
    double ss = 0.0;
    #pragma unroll
    for (int e = 0; e < 8; ++e) { double x = (double)row[e]; ss += x * x; }
    double inv = 1.0 / fmax(sqrt(ss), 1e-12);
    #pragma unroll
    for (int e = 0; e < 8; ++e) cbn[(j << 3) + e] = (double)row[e] * inv;
  } else if (i < 202784) {               // zero the 32 loss accumulators
    loss_slots[i - 202752] = 0.0f;
  }
}

__global__ __launch_bounds__(256) void vq_main(
    const float* __restrict__ z, const float* __restrict__ cb,
    const float* __restrict__ pd_p, const float* __restrict__ pu_p,
    const double* __restrict__ cbn,
    float* __restrict__ out, float* __restrict__ loss_slots)
{
  __shared__ double part_d[16 * 128];   // 16 KB reduction buffer
  __shared__ double ze_d[TT * 8];
  __shared__ float  zq_s[TT * 8];
  __shared__ float  lossv[TT];

  const int tid  = threadIdx.x;
  const int tl   = tid & 127;    // index within e-half
  const int eh   = tid >> 7;     // which half of e (0: e0..3, 1: e4..7)
  const int lane = tid & 63;
  const int wv   = tid >> 6;     // wave id (phase 2: wave owns frame t=wv)
  const int tc   = blockIdx.x;   // 0..31 (chunk of TT=4 grouped frames)
  const int g    = blockIdx.y;   // 0..5
  const int b    = blockIdx.z;   // 0..15

  const float* zb = z + (size_t)b * (SEQ_ * C_);

  // ---------- phase 1: z_e partials, z direct-from-global, fp64 accum -------
  // thread owns dp pairs {i*256 + 2*tl, +1} for i in [0,8), e-range eh*4..+3.
  // pd read ONCE per block (each 16B half-row by exactly one thread).
  double acc[TT][4];
  #pragma unroll
  for (int t = 0; t < TT; ++t)
    #pragma unroll
    for (int j = 0; j < 4; ++j) acc[t][j] = 0.0;

  {
    const int hofs = tl >> 6;            // dp0>>7 parity
    const int ul2  = (tl & 63) << 1;
    const float* zbase = zb + (size_t)(tc * (TT * OV_)) * 192 + (g << 7) + ul2;
    const float* pdg = pd_p + ((g << 11) << 3) + (eh << 2);

    #pragma unroll 2
    for (int i = 0; i < 8; ++i) {
      const int h = (i << 1) + hofs;
      const float* zp = zbase + (size_t)h * (512 * 192);
      float2 zv[TT];
      #pragma unroll
      for (int t = 0; t < TT; ++t)
        zv[t] = *(const float2*)(zp + t * (OV_ * 192));
      const int dp0 = (i << 8) + (tl << 1);
      const float4 pa = *(const float4*)(pdg + (dp0 << 3));        // row dp0, e-half
      const float4 pb = *(const float4*)(pdg + ((dp0 + 1) << 3));  // row dp0+1, e-half
      #pragma unroll
      for (int t = 0; t < TT; ++t) {
        const double z0 = (double)zv[t].x, z1 = (double)zv[t].y;
        acc[t][0] = fma(z0, (double)pa.x, acc[t][0]);
        acc[t][1] = fma(z0, (double)pa.y, acc[t][1]);
        acc[t][2] = fma(z0, (double)pa.z, acc[t][2]);
        acc[t][3] = fma(z0, (double)pa.w, acc[t][3]);
        acc[t][0] = fma(z1, (double)pb.x, acc[t][0]);
        acc[t][1] = fma(z1, (double)pb.y, acc[t][1]);
        acc[t][2] = fma(z1, (double)pb.z, acc[t][2]);
        acc[t][3] = fma(z1, (double)pb.w, acc[t][3]);
      }
    }
  }

  // ---------- phase 1.5: block reduction, 2 rounds x 16 (t,e)-slots, fp64 ---
  // slot = tl2*8 + eh*4 + j  (tl2 = t within round pair); 128 partials/slot.
  #pragma unroll
  for (int r = 0; r < 2; ++r) {
    __syncthreads();
    #pragma unroll
    for (int tl2 = 0; tl2 < 2; ++tl2)
      #pragma unroll
      for (int j = 0; j < 4; ++j)
        part_d[(((tl2 << 3) + (eh << 2) + j) << 7) + tl] = acc[(r << 1) + tl2][j];
    __syncthreads();
    const int slot = tid >> 4, jj = tid & 15;
    double partial = 0.0;
    #pragma unroll
    for (int s = 0; s < 8; ++s)
      partial += part_d[(slot << 7) + (s << 4) + jj];
    partial += __shfl_down(partial, 8, 16);
    partial += __shfl_down(partial, 4, 16);
    partial += __shfl_down(partial, 2, 16);
    partial += __shfl_down(partial, 1, 16);
    if (jj == 0) ze_d[(r << 4) + slot] = partial;   // kk = t*8+e = r*16 + slot
  }
  __syncthreads();

  // ---------- phase 2: argmax over 1024 codes (fp64 sim, first-max tie-break)
  // wave wv owns frame t=wv; lane scans 16 rows (k = q*64 + lane, q ascending
  // -> strict > keeps min k within lane); ONE row in flight to cap registers.
  {
    double zr[8];
    #pragma unroll
    for (int e = 0; e < 8; ++e) zr[e] = ze_d[wv * 8 + e];

    double best = -1.0e300; int bkey = 0x7fffffff;
    #pragma unroll 1
    for (int q = 0; q < 16; ++q) {
      const double* cr = cbn + (((g << 10) + (q << 6) + lane) << 3);
      double s = 0.0;
      #pragma unroll
      for (int e = 0; e < 8; ++e) s = fma(zr[e], cr[e], s);
      const int k = (q << 6) + lane;
      if (s > best) { best = s; bkey = k; }
    }
    #pragma unroll
    for (int m = 32; m >= 1; m >>= 1) {
      double os = __shfl_xor(best, m);
      int    ok = __shfl_xor(bkey, m);
      if (os > best || (os == best && ok < bkey)) { best = os; bkey = ok; }
    }
    if (lane == 0) {
      const float* crow = cb + (((g << 10) + bkey) << 3);   // RAW codebook row
      double l = 0.0;
      #pragma unroll
      for (int e = 0; e < 8; ++e) {
        float qv = crow[e];
        zq_s[wv * 8 + e] = qv;
        double dd = zr[e] - (double)qv;
        l = fma(dd, dd, l);
      }
      lossv[wv] = (float)l;
    }
  }
  __syncthreads();
  if (tid == 0) {
    float l = (lossv[0] + lossv[1] + lossv[2] + lossv[3]) * (1.0f / (T_ * D_ * G_));
    atomicAdd(loss_slots + b, l);        // commitment
    atomicAdd(loss_slots + 16 + b, l);   // codebook loss (numerically identical)
  }

  // ---------- phase 3: out = z_q @ proj_up, scatter-coalesced ----------
  float zqr[TT][8];
  #pragma unroll
  for (int t = 0; t < TT; ++t)
    #pragma unroll
    for (int e = 0; e < 8; ++e) zqr[t][e] = zq_s[t * 8 + e];

  #pragma unroll
  for (int j = 0; j < 8; ++j) {
    int dp = j * 256 + tid;
    int h = dp >> 7, ul = dp & 127;
    int u = (g << 7) + ul;
    int o = (u * 683) >> 17;
    int c = u - o * 192;
    float pv[8];
    #pragma unroll
    for (int e = 0; e < 8; ++e) pv[e] = pu_p[(g << 14) + (e << 11) + dp];
    size_t base = ((size_t)(b * SEQ_) + h * 512 + tc * (TT * OV_) + o) * 192 + c;
    #pragma unroll
    for (int t = 0; t < TT; ++t) {
      float v = 0.f;
      #pragma unroll
      for (int e = 0; e < 8; ++e) v = fmaf(zqr[t][e], pv[e], v);
      out[base + (size_t)(t * OV_ * 192)] = v;
    }
  }
}

extern "C" void kernel_launch(void* const* d_in, const int* in_sizes, int n_in,
                              void* d_out, int out_size, void* d_ws, size_t ws_size,
                              hipStream_t stream)
{
  const float* z  = (const float*)d_in[0];   // (B, SEQ, C)
  const float* pd = (const float*)d_in[1];   // (G, DG, D)
  const float* pu = (const float*)d_in[2];   // (G, D, DG)
  const float* cb = (const float*)d_in[3];   // (G, K, D)
  float* out = (float*)d_out;
  float* loss_slots = out + OUT_ELEMS;       // 16 commitment + 16 codebook

  float*  pd_p = (float*)d_ws;
  float*  pu_p = pd_p + 98304;
  double* cbn  = (double*)(pu_p + 98304);

  vq_prep<<<793, 256, 0, stream>>>(pd, pu, cb, pd_p, pu_p, cbn, loss_slots);
  dim3 grid(T_ / TT, G_, B_);
  vq_main<<<grid, 256, 0, stream>>>(z, cb, pd_p, pu_p, cbn, out, loss_slots);
}